// Round 15
// baseline (795.717 us; speedup 1.0000x reference)
//
#include <hip/hip_runtime.h>
#include <hip/hip_bf16.h>

// Problem constants
#define Bb    2
#define Nn    1024
#define NCTXc 2048
#define DIMd  1024
#define Hh    16
#define DHd   64
#define NMEM  16
#define Jv    (NMEM + NCTXc)   // 2064 valid kv rows
#define JP    2112             // padded to multiple of 64
#define HJP   (Hh * JP)        // 33792: row stride of S ([b][i][h][j])
#define L2E   1.44269504088896f
#define LDH   1048             // staged half-row stride (1040 cols + 8 pad; 16B aligned, 2-way banks)

typedef _Float16 f16;
typedef _Float16 half8 __attribute__((ext_vector_type(8)));
typedef _Float16 half4 __attribute__((ext_vector_type(4)));
typedef float    f32x4 __attribute__((ext_vector_type(4)));

__device__ __forceinline__ float bf2f(unsigned short u){
  union { unsigned int i; float f; } v; v.i = ((unsigned)u) << 16; return v.f;
}
// sanitize: NaN -> 0, clamp to f16-safe range (identity on well-formed inputs)
__device__ __forceinline__ float fin(float v){
  v = (v == v) ? v : 0.f;
  return fminf(fmaxf(v, -65504.f), 65504.f);
}
// dtype-flag-dispatched input read. isf32: 1 = buffer holds float32, 0 = bf16.
__device__ __forceinline__ float ldin(const void* p, long i, int isf32){
  return isf32 ? ((const float*)p)[i] : bf2f(((const unsigned short*)p)[i]);
}
__device__ __forceinline__ half8 h8zero(){
  half8 v;
  #pragma unroll
  for (int j = 0; j < 8; j++) v[j] = (f16)0.f;
  return v;
}
// async global->LDS 16B copy (linear LDS dest = wave-uniform base + lane*16)
__device__ __forceinline__ void gload16(const f16* g, f16* l){
  __builtin_amdgcn_global_load_lds(
      (const __attribute__((address_space(1))) unsigned int*)g,
      (__attribute__((address_space(3))) unsigned int*)l, 16, 0, 0);
}

// ---------------- dtype probe ----------------
__global__ void detect_dtype(const void* __restrict__ p, int* __restrict__ flag, int n){
  const unsigned short* ub = (const unsigned short*)p;
  const float* fp = (const float*)p;
  int t = threadIdx.x;
  float bb = 0.f, bf = 0.f;
  for (int i = t; i < n; i += 64){
    float vb = bf2f(ub[i]);
    if (!(vb == vb) || fabsf(vb) > 1000.f) bb += 1.f;
    float vf = fp[i];
    if (!(vf == vf) || fabsf(vf) > 1000.f) bf += 1.f;
  }
  #pragma unroll
  for (int off = 32; off; off >>= 1){ bb += __shfl_xor(bb, off); bf += __shfl_xor(bf, off); }
  if (t == 0) *flag = (bf < bb) ? 1 : 0;
}

// ---------------- any-dtype -> f16 convert (sanitized), element offset in src dtype ----------------
__global__ __launch_bounds__(256) void cvt_any(const void* __restrict__ in, f16* __restrict__ out,
                                               long n, long off, const int* __restrict__ flag){
  int isf = *flag;
  long stride = (long)gridDim.x * 256;
  for (long i = (long)blockIdx.x * 256 + threadIdx.x; i < n; i += stride)
    out[i] = (f16)fin(ldin(in, off + i, isf));
}

// ---------------- any-dtype -> f32 convert (sanitized, small params) ----------------
__global__ __launch_bounds__(256) void cvt32_any(const void* __restrict__ in, float* __restrict__ out,
                                                 long n, const int* __restrict__ flag){
  int isf = *flag;
  long stride = (long)gridDim.x * 256;
  for (long i = (long)blockIdx.x * 256 + threadIdx.x; i < n; i += stride)
    out[i] = fin(ldin(in, i, isf));
}

// ---------------- transpose + convert: out[c][r] = in[r][c] ----------------
__global__ __launch_bounds__(256) void transpose_any(const void* __restrict__ in,
                                                     f16* __restrict__ out,
                                                     int Cc, long ldo,
                                                     const int* __restrict__ flag){
  __shared__ f16 tile[32][33];
  int isf = *flag;
  int r0 = blockIdx.y * 32, c0 = blockIdx.x * 32;
  int tr = threadIdx.x >> 5, tc = threadIdx.x & 31;
  #pragma unroll
  for (int k = 0; k < 4; k++){
    int r = tr + k * 8;
    tile[r][tc] = (f16)fin(ldin(in, (long)(r0 + r) * Cc + c0 + tc, isf));
  }
  __syncthreads();
  #pragma unroll
  for (int k = 0; k < 4; k++){
    int r = tr + k * 8;
    out[(long)(c0 + r) * ldo + r0 + tc] = tile[tc][r];
  }
}

// ---------------- 128x128-tile GEMM (f16 in/out): C[m][n] = sum_k A[m][k]*Bt[n][k] ----------------
// m97-style: BK=32, global_load_lds width 16 into LINEAR [128][32] LDS, 4 waves of 4x4
// 16x16x32 fragments, 2-barrier K-loop. M,N multiples of 128; K multiple of 32.
__global__ __launch_bounds__(256) void gemm128(
    const f16* __restrict__ A, const f16* __restrict__ Bt, f16* __restrict__ C,
    int K, long lda, long ldb, long ldc)
{
  __shared__ __align__(16) f16 As[128 * 32];
  __shared__ __align__(16) f16 Bs[128 * 32];
  long m0 = (long)blockIdx.y * 128, n0 = (long)blockIdx.x * 128;
  int t = threadIdx.x;
  int wave = t >> 6, lane = t & 63;
  int wm = (wave >> 1) * 64, wn = (wave & 1) * 64;
  int fr = lane & 15, fq = lane >> 4;
  int sr = t >> 2, scc = (t & 3) * 8;   // staging: 4 thr/row x 8 f16, 64 rows/issue

  f32x4 acc[4][4];
  #pragma unroll
  for (int a = 0; a < 4; a++)
    #pragma unroll
    for (int b = 0; b < 4; b++) acc[a][b] = (f32x4){0.f, 0.f, 0.f, 0.f};

  const f16* Ap  = A  + (m0 + sr) * lda + scc;
  const f16* Ap2 = Ap + 64 * lda;
  const f16* Bp  = Bt + (n0 + sr) * ldb + scc;
  const f16* Bp2 = Bp + 64 * ldb;
  f16* Ad  = As + t * 8;        // byte t*16: linear dest (row-major [64][32])
  f16* Ad2 = As + 2048 + t * 8;
  f16* Bd  = Bs + t * 8;
  f16* Bd2 = Bs + 2048 + t * 8;

  for (int k0 = 0; k0 < K; k0 += 32){
    __syncthreads();              // prev tile fully consumed before overwrite
    gload16(Ap  + k0, Ad);
    gload16(Ap2 + k0, Ad2);
    gload16(Bp  + k0, Bd);
    gload16(Bp2 + k0, Bd2);
    __syncthreads();              // drains vmcnt(0): loads landed
    half8 bfr[4];
    #pragma unroll
    for (int tj = 0; tj < 4; tj++)
      bfr[tj] = *(const half8*)&Bs[(wn + 16 * tj + fr) * 32 + fq * 8];
    #pragma unroll
    for (int ti = 0; ti < 4; ti++){
      half8 af = *(const half8*)&As[(wm + 16 * ti + fr) * 32 + fq * 8];
      #pragma unroll
      for (int tj = 0; tj < 4; tj++)
        acc[ti][tj] = __builtin_amdgcn_mfma_f32_16x16x32_f16(af, bfr[tj], acc[ti][tj], 0, 0, 0);
    }
  }
  #pragma unroll
  for (int ti = 0; ti < 4; ti++)
    #pragma unroll
    for (int tj = 0; tj < 4; tj++)
      #pragma unroll
      for (int r = 0; r < 4; r++){
        long row = m0 + wm + 16 * ti + fq * 4 + r;
        long col = n0 + wn + 16 * tj + fr;
        C[row * ldc + col] = (f16)acc[ti][tj][r];
      }
}

// ---------------- same, dtype-dispatched output store (final GEMM) ----------------
__global__ __launch_bounds__(256) void gemm128_dyn(
    const f16* __restrict__ A, const f16* __restrict__ Bt, void* __restrict__ C,
    int K, long lda, long ldb, long ldc, const int* __restrict__ flag)
{
  int isf = *flag;
  __shared__ __align__(16) f16 As[128 * 32];
  __shared__ __align__(16) f16 Bs[128 * 32];
  long m0 = (long)blockIdx.y * 128, n0 = (long)blockIdx.x * 128;
  int t = threadIdx.x;
  int wave = t >> 6, lane = t & 63;
  int wm = (wave >> 1) * 64, wn = (wave & 1) * 64;
  int fr = lane & 15, fq = lane >> 4;
  int sr = t >> 2, scc = (t & 3) * 8;

  f32x4 acc[4][4];
  #pragma unroll
  for (int a = 0; a < 4; a++)
    #pragma unroll
    for (int b = 0; b < 4; b++) acc[a][b] = (f32x4){0.f, 0.f, 0.f, 0.f};

  const f16* Ap  = A  + (m0 + sr) * lda + scc;
  const f16* Ap2 = Ap + 64 * lda;
  const f16* Bp  = Bt + (n0 + sr) * ldb + scc;
  const f16* Bp2 = Bp + 64 * ldb;
  f16* Ad  = As + t * 8;
  f16* Ad2 = As + 2048 + t * 8;
  f16* Bd  = Bs + t * 8;
  f16* Bd2 = Bs + 2048 + t * 8;

  for (int k0 = 0; k0 < K; k0 += 32){
    __syncthreads();
    gload16(Ap  + k0, Ad);
    gload16(Ap2 + k0, Ad2);
    gload16(Bp  + k0, Bd);
    gload16(Bp2 + k0, Bd2);
    __syncthreads();
    half8 bfr[4];
    #pragma unroll
    for (int tj = 0; tj < 4; tj++)
      bfr[tj] = *(const half8*)&Bs[(wn + 16 * tj + fr) * 32 + fq * 8];
    #pragma unroll
    for (int ti = 0; ti < 4; ti++){
      half8 af = *(const half8*)&As[(wm + 16 * ti + fr) * 32 + fq * 8];
      #pragma unroll
      for (int tj = 0; tj < 4; tj++)
        acc[ti][tj] = __builtin_amdgcn_mfma_f32_16x16x32_f16(af, bfr[tj], acc[ti][tj], 0, 0, 0);
    }
  }
  #pragma unroll
  for (int ti = 0; ti < 4; ti++)
    #pragma unroll
    for (int tj = 0; tj < 4; tj++)
      #pragma unroll
      for (int r = 0; r < 4; r++){
        long row = m0 + wm + 16 * ti + fq * 4 + r;
        long col = n0 + wn + 16 * tj + fr;
        float v = acc[ti][tj][r];
        if (isf) ((float*)C)[row * ldc + col] = v;
        else     ((__hip_bfloat16*)C)[row * ldc + col] = __float2bfloat16(v);
      }
}

// ---------------- generic batched GEMM: C[m][n] = sum_k A[m][k]*Bt[n][k], z=(zb,zh) ----------------
// gload16 (async DMA) staging into LINEAR [64][32] LDS; C-tile staged through LDS -> half8
// coalesced stores. Arithmetic order identical to previous versions.
__global__ __launch_bounds__(256) void gemm_bt(
    const f16* __restrict__ A, const f16* __restrict__ Bt, f16* __restrict__ C,
    int K, long lda, long ldb, long ldc,
    long sAb, long sBb, long sCb, long sAh, long sBh, long sCh, int nh)
{
  int z = blockIdx.z;
  int zb = z / nh, zh = z - zb * nh;
  A  += (long)zb * sAb + (long)zh * sAh;
  Bt += (long)zb * sBb + (long)zh * sBh;
  C  += (long)zb * sCb + (long)zh * sCh;
  long m0 = (long)blockIdx.y * 64, n0 = (long)blockIdx.x * 64;

  __shared__ __align__(16) f16 As[64 * 32];
  __shared__ __align__(16) f16 Bs[64 * 32];
  __shared__ __align__(16) f16 Cs[64 * 64];
  int t = threadIdx.x;
  int wave = t >> 6, lane = t & 63;
  int wm = (wave >> 1) * 32, wn = (wave & 1) * 32;
  int fr = lane & 15, fq = lane >> 4;
  int sr = t >> 2, scc = (t & 3) * 8;

  f32x4 acc[2][2];
  #pragma unroll
  for (int a = 0; a < 2; a++)
    #pragma unroll
    for (int b = 0; b < 2; b++) acc[a][b] = (f32x4){0.f, 0.f, 0.f, 0.f};

  const f16* Ap = A  + (m0 + sr) * lda + scc;
  const f16* Bp = Bt + (n0 + sr) * ldb + scc;
  f16* Ad = As + t * 8;          // byte t*16: linear dest (row-major [64][32])
  f16* Bd = Bs + t * 8;

  for (int k0 = 0; k0 < K; k0 += 32){
    __syncthreads();             // prev tile fully consumed before overwrite
    gload16(Ap + k0, Ad);
    gload16(Bp + k0, Bd);
    __syncthreads();             // drains vmcnt(0): loads landed
    #pragma unroll
    for (int ti = 0; ti < 2; ti++){
      half8 af = *(const half8*)&As[(wm + 16 * ti + fr) * 32 + fq * 8];
      #pragma unroll
      for (int tj = 0; tj < 2; tj++){
        half8 bf = *(const half8*)&Bs[(wn + 16 * tj + fr) * 32 + fq * 8];
        acc[ti][tj] = __builtin_amdgcn_mfma_f32_16x16x32_f16(af, bf, acc[ti][tj], 0, 0, 0);
      }
    }
  }
  // stage C tile in LDS (value-identical), then coalesced half8 stores
  __syncthreads();
  #pragma unroll
  for (int ti = 0; ti < 2; ti++)
    #pragma unroll
    for (int tj = 0; tj < 2; tj++)
      #pragma unroll
      for (int r = 0; r < 4; r++)
        Cs[(wm + 16 * ti + fq * 4 + r) * 64 + wn + 16 * tj + fr] = (f16)acc[ti][tj][r];
  __syncthreads();
  #pragma unroll
  for (int it = 0; it < 2; it++){
    int idx = t + it * 256;          // 0..511: row = idx>>3, col8 = (idx&7)*8
    int row = idx >> 3, c8 = (idx & 7) * 8;
    *(half8*)(C + (m0 + row) * ldc + n0 + c8) = *(const half8*)&Cs[row * 64 + c8];
  }
}

// ---------------- q: l2norm per head + fold per-head scale (qp row stride 2048) ----------------
__global__ __launch_bounds__(256) void qn_build(const f16* __restrict__ qp, f16* __restrict__ qn,
                                                const float* __restrict__ scale_p){
  int row = blockIdx.x;                 // 0..B*N-1
  int wave = threadIdx.x >> 6, lane = threadIdx.x & 63;
  #pragma unroll
  for (int hh = 0; hh < 4; hh++){
    int h = wave * 4 + hh;
    float v = (float)qp[(long)row * 2048 + h * 64 + lane];
    float ss = v * v;
    #pragma unroll
    for (int off = 32; off; off >>= 1) ss += __shfl_xor(ss, off);
    float sc = 1.0f / fmaxf(__expf(scale_p[h]), 0.01f);
    float o = v / fmaxf(sqrtf(ss), 1e-12f) * sc;
    qn[(long)row * 1024 + h * 64 + lane] = (f16)o;
  }
}

// ---------------- k buffer: mem_k prepended, l2norm, zero pad (kp row stride 2048) ----------------
__global__ __launch_bounds__(256) void kbuf_build(const f16* __restrict__ kp,
                                                  const f16* __restrict__ mem_k,
                                                  f16* __restrict__ kbuf){
  int id = blockIdx.x * 4 + (threadIdx.x >> 6);  // (b*JP + j)*16 + h
  int lane = threadIdx.x & 63;
  int h = id & 15; int bj = id >> 4; int j = bj % JP; int b = bj / JP;
  float v;
  if (j < NMEM)              v = (float)mem_k[(h * NMEM + j) * 64 + lane];
  else if (j < NMEM + NCTXc) v = (float)kp[((long)b * NCTXc + (j - NMEM)) * 2048 + h * 64 + lane];
  else                       v = 0.f;
  float ss = v * v;
  #pragma unroll
  for (int off = 32; off; off >>= 1) ss += __shfl_xor(ss, off);
  float o = v / fmaxf(sqrtf(ss), 1e-12f);
  kbuf[((long)b * JP + j) * 1024 + h * 64 + lane] = (f16)o;
}

// ---------------- v buffer, transposed per head: vt[(b,h)][d][j] (vp row stride 2048) ----------------
__global__ __launch_bounds__(256) void vt_build(const f16* __restrict__ vp,
                                                const f16* __restrict__ mem_v,
                                                f16* __restrict__ vt){
  __shared__ f16 tile[64][72];
  int id = blockIdx.x;
  int jt = id % (JP / 64); int h = (id / (JP / 64)) & 15; int b = id / (16 * (JP / 64));
  int j0 = jt * 64;
  int t = threadIdx.x;
  #pragma unroll
  for (int rep = 0; rep < 2; rep++){
    int idx = t + rep * 256;
    int jj = idx >> 3, c8 = (idx & 7) * 8;
    int j = j0 + jj;
    half8 v;
    if (j < NMEM){
      v = *(const half8*)(mem_v + (h * NMEM + j) * 64 + c8);
    } else if (j < NMEM + NCTXc){
      v = *(const half8*)(vp + ((long)b * NCTXc + (j - NMEM)) * 2048 + h * 64 + c8);
    } else {
      v = h8zero();
    }
    *(half8*)&tile[jj][c8] = v;
  }
  __syncthreads();
  #pragma unroll
  for (int rep = 0; rep < 2; rep++){
    int idx = t + rep * 256;
    int d = idx >> 3, j8 = (idx & 7) * 8;
    half8 o;
    #pragma unroll
    for (int k = 0; k < 8; k++) o[k] = tile[j8 + k][d];
    *(half8*)(vt + (((long)(b * 16 + h) * 64 + d) * JP) + j0 + j8) = o;
  }
}

// ---------------- fused talking-heads softmax via MFMA, v6 ----------------
// v5's issue-early staging + halved LDS (T14 full split): half-0 staged to the single
// 34 KB tile, half-1 issued to REGISTERS up front (in flight during half-0 compute),
// then written-late into the same tile after half-0 is consumed. LDS 68.6 -> ~35 KB
// doubles residency to 4 blocks/CU. Values bit-identical to v5.
__global__ __launch_bounds__(512) void softmax_mfma(
    f16* __restrict__ S,
    const float* __restrict__ th_pre,
    const float* __restrict__ th_post,
    const float* __restrict__ hs)
{
  __shared__ __align__(16) f16 tile[16 * LDH];   // 33536 B, reused for both halves
  __shared__ float msh[8][16], lsh[8][16];
  __shared__ float Mf[16], Li[16];

  int t = threadIdx.x, wave = t >> 6, lane = t & 63;
  int r16 = lane & 15;                    // fragment row/col index
  int hb4 = (lane >> 4) * 4;              // k-group base (4 heads per lane group)
  int sr  = t >> 5, sc = t & 31;          // staging: row 0..15, col-thread 0..31
  f16* Srow = S + (long)blockIdx.x * HJP;

  // pre-mix A fragment: A[g = r16][h = hb4+j] = th_pre[g][h], hi/lo f16 split
  half4 ahi, alo;
  #pragma unroll
  for (int j = 0; j < 4; j++){
    float a = th_pre[r16 * 16 + hb4 + j];
    ahi[j] = (f16)a; alo[j] = (f16)(a - (float)ahi[j]);
  }

  float m[4], l[4];
  #pragma unroll
  for (int r = 0; r < 4; r++){ m[r] = -1e30f; l[r] = 0.f; }

  half4 msave[17];
  const f32x4 z4 = (f32x4){0.f, 0.f, 0.f, 0.f};

  // ---- issue half-1 global loads into registers FIRST (latency hidden under half-0) ----
  half8 r1[4];
  #pragma unroll
  for (int it = 0; it < 4; it++){
    int c8 = sc + it * 32;
    r1[it] = *(const half8*)(Srow + (long)sr * JP + 1040 + c8 * 8);
  }
  // ---- stage half-0 into LDS ----
  #pragma unroll
  for (int it = 0; it < 5; it++){
    int c8 = sc + it * 32;
    if (c8 < 130)
      *(half8*)&tile[sr * LDH + c8 * 8] = *(const half8*)(Srow + (long)sr * JP + c8 * 8);
  }
  __syncthreads();

  // ---- sweep 1, half 0: premix + stats (chunks 0..64) ----
  #pragma unroll
  for (int cc = 0; cc < 9; cc++){
    int c = wave + cc * 8;
    if (c < 65){
      int lc = c * 16 + r16;
      half4 b;
      #pragma unroll
      for (int j = 0; j < 4; j++) b[j] = tile[(hb4 + j) * LDH + lc];
      f32x4 acc = __builtin_amdgcn_mfma_f32_16x16x16f16(alo, b, z4, 0, 0, 0);
      acc = __builtin_amdgcn_mfma_f32_16x16x16f16(ahi, b, acc, 0, 0, 0);
      half4 hh;
      #pragma unroll
      for (int r = 0; r < 4; r++){
        float u = fminf(fmaxf(acc[r], -60.f), 78.f);
        m[r] = fmaxf(m[r], u);
        l[r] += exp2f(u * L2E);
        hh[r] = (f16)u;
      }
      msave[cc] = hh;
    }
  }
  __syncthreads();                       // tile fully consumed
  // ---- write-late: half-1 registers -> tile ----
  #pragma unroll
  for (int it = 0; it < 4; it++){
    int c8 = sc + it * 32;
    *(half8*)&tile[sr * LDH + c8 * 8] = r1[it];
  }
  __syncthreads();
  // ---- sweep 1, half 1: premix + stats (chunks 65..128, exactly 8/wave) ----
  #pragma unroll
  for (int cc = 0; cc < 8; cc++){
    int c = 65 + wave + cc * 8;
    int lc = c * 16 - 1040 + r16;
    half4 b;
    #pragma unroll
    for (int j = 0; j < 4; j++) b[j] = tile[(hb4 + j) * LDH + lc];
    f32x4 acc = __builtin_amdgcn_mfma_f32_16x16x16f16(alo, b, z4, 0, 0, 0);
    acc = __builtin_amdgcn_mfma_f32_16x16x16f16(ahi, b, acc, 0, 0, 0);
    half4 hh;
    #pragma unroll
    for (int r = 0; r < 4; r++){
      float u = fminf(fmaxf(acc[r], -60.f), 78.f);
      m[r] = fmaxf(m[r], u);
      l[r] += exp2f(u * L2E);
      hh[r] = (f16)u;
    }
    msave[9 + cc] = hh;
  }

  // ---- reduce (m,l): plain fmax/add butterfly within 16-lane groups, then waves ----
  #pragma unroll
  for (int off = 1; off < 16; off <<= 1){
    #pragma unroll
    for (int r = 0; r < 4; r++){
      m[r] = fmaxf(m[r], __shfl_xor(m[r], off));
      l[r] += __shfl_xor(l[r], off);
    }
  }
  if (r16 == 0){
    #pragma unroll
    for (int r = 0; r < 4; r++){ msh[wave][hb4 + r] = m[r]; lsh[wave][hb4 + r] = l[r]; }
  }
  __syncthreads();
  if (t < 16){
    float mf_ = msh[0][t], lf = lsh[0][t];
    #pragma unroll
    for (int w = 1; w < 8; w++){ mf_ = fmaxf(mf_, msh[w][t]); lf += lsh[w][t]; }
    Mf[t] = mf_;
    Li[t] = fin(exp2f(mf_ * L2E) / lf);
  }
  __syncthreads();

  // post-mix A fragment: C[p = r16][g = hb4+j] = th_post[p][g]*hs[p]*2^(M_g*L2E)/l_g
  half4 chi, clo;
  float hsv = hs[r16];
  #pragma unroll
  for (int j = 0; j < 4; j++){
    float cc2 = th_post[r16 * 16 + hb4 + j] * hsv * Li[hb4 + j];
    chi[j] = (f16)cc2; clo[j] = (f16)(cc2 - (float)chi[j]);
  }
  float mf[4];
  #pragma unroll
  for (int r = 0; r < 4; r++) mf[r] = Mf[hb4 + r];

  // ---- sweep 2: register-only exp + post-mix + store ----
  #pragma unroll
  for (int cc = 0; cc < 9; cc++){
    int c = wave + cc * 8;
    if (c < 65){
      half4 h4 = msave[cc];
      half4 ehi, elo;
      #pragma unroll
      for (int r = 0; r < 4; r++){
        float e = exp2f(((float)h4[r] - mf[r]) * L2E);
        ehi[r] = (f16)e; elo[r] = (f16)(e - (float)ehi[r]);
      }
      f32x4 o = __builtin_amdgcn_mfma_f32_16x16x16f16(chi, ehi, z4, 0, 0, 0);
      o = __builtin_amdgcn_mfma_f32_16x16x16f16(clo, ehi, o, 0, 0, 0);
      o = __builtin_amdgcn_mfma_f32_16x16x16f16(chi, elo, o, 0, 0, 0);
      int col = c * 16 + r16;
      #pragma unroll
      for (int r = 0; r < 4; r++) Srow[(hb4 + r) * JP + col] = (f16)o[r];
    }
  }
  #pragma unroll
  for (int cc = 0; cc < 8; cc++){
    int c = 65 + wave + cc * 8;
    half4 h4 = msave[9 + cc];
    half4 ehi, elo;
    #pragma unroll
    for (int r = 0; r < 4; r++){
      float e = exp2f(((float)h4[r] - mf[r]) * L2E);
      ehi[r] = (f16)e; elo[r] = (f16)(e - (float)ehi[r]);
    }
    f32x4 o = __builtin_amdgcn_mfma_f32_16x16x16f16(chi, ehi, z4, 0, 0, 0);
    o = __builtin_amdgcn_mfma_f32_16x16x16f16(clo, ehi, o, 0, 0, 0);
    o = __builtin_amdgcn_mfma_f32_16x16x16f16(chi, elo, o, 0, 0, 0);
    int col = c * 16 + r16;
    #pragma unroll
    for (int r = 0; r < 4; r++) Srow[(hb4 + r) * JP + col] = (f16)o[r];
  }
}

// ---------------- launch ----------------
extern "C" void kernel_launch(void* const* d_in, const int* in_sizes, int n_in,
                              void* d_out, int out_size, void* d_ws, size_t ws_size,
                              hipStream_t stream)
{
  (void)in_sizes; (void)n_in; (void)out_size; (void)ws_size;
  int* flag = (int*)d_ws;
  f16* ws   = (f16*)d_ws + 8;        // keep 16B alignment
  f16* wT   = ws;                    //  6,291,456: slots [wq1T][wq2T][wk1T][wv1T][wk2T][wv2T]
  f16* woT  = wT   + 6291456;        //  2,097,152 ([1024 x 2048])
  f16* qn   = woT  + 2097152;        //  4,194,304 (qn layer0, qn layer1)
  f16* kbuf = qn   + 4194304;        //  4,325,376
  f16* vt   = kbuf + 4325376;        //  4,325,376
  f16* av   = vt   + 4325376;        //  4,194,304 ([B*N x 2048])
  f16* memc = av   + 4194304;        //  65,536 (mem_k1,mem_v1,mem_k2,mem_v2)
  float* parc = (float*)(memc + 65536); // 1088 f32 (th_pre1,th_post1,th_pre2,th_post2,sc1,sc2,hs1,hs2)
  f16* S    = (f16*)(parc + 1088);   //  69,206,016 ([b][i][16][JP])
  // scratch aliased inside S (all dead before the score GEMM writes S):
  f16* tmpkv = S;                    //  8,388,608 ([4096 x 2048]: k cols 0..1023, v cols 1024..2047)
  f16* tmpq  = S + 8388608;          //  4,194,304 ([2048 x 2048]: q1 cols 0..1023, q2 cols 1024..2047)
  f16* xf    = S + 12582912;         //  2,097,152 (x as f16)
  f16* cxf   = S + 14680064;         //  4,194,304 (ctx layer slice as f16)

  // dtype probe on x
  detect_dtype<<<1, 64, 0, stream>>>(d_in[0], flag, 4096);

  for (int i = 0; i < 4; i++)  // mem_k1, mem_v1, mem_k2, mem_v2
    cvt_any<<<16, 256, 0, stream>>>(d_in[14 + i], memc + (long)i * 16384, 16384, 0, flag);
  { // small params -> f32 pack
    const int  src[8] = {8, 9, 10, 11, 12, 13, 18, 19};
    const long off[8] = {0, 256, 512, 768, 1024, 1040, 1056, 1072};
    const long cnt[8] = {256, 256, 256, 256, 16, 16, 16, 16};
    for (int i = 0; i < 8; i++)
      cvt32_any<<<1, 256, 0, stream>>>(d_in[src[i]], parc + off[i], cnt[i], flag);
  }

  // transpose weights into contiguity-friendly slots:
  // input order d_in[2..7] = wq1,wk1,wv1,wq2,wk2,wv2 -> slots {0,2,3,1,4,5}
  {
    const int slot[6] = {0, 2, 3, 1, 4, 5};
    for (int i = 0; i < 6; i++)
      transpose_any<<<dim3(32, 32), 256, 0, stream>>>(d_in[2 + i],
                                                      wT + (long)slot[i] * 1048576, 1024, 1024, flag);
  }
  for (int L = 0; L < 2; L++)
    transpose_any<<<dim3(32, 32), 256, 0, stream>>>(d_in[20 + L],
                                                    woT + (long)L * 1024, 1024, 2048, flag);

  // x -> f16 once; q projection for BOTH layers: [2048x1024] @ [1024x2048]
  cvt_any<<<1024, 256, 0, stream>>>(d_in[0], xf, 2097152, 0, flag);
  gemm128<<<dim3(16, 16), 256, 0, stream>>>(xf, wT, tmpq, 1024, 1024, 1024, 2048);
  for (int L = 0; L < 2; L++)
    qn_build<<<Bb * Nn, 256, 0, stream>>>(tmpq + (long)L * 1024, qn + (long)L * 2097152,
                                          parc + 1024 + (long)L * 16);

  for (int L = 0; L < 2; L++){
    const float* thpre  = parc + (long)L * 512;
    const float* thpost = parc + (long)L * 512 + 256;
    const float* hsp    = parc + 1056 + (long)L * 16;
    const f16* mem_k = memc + (long)(2 * L) * 16384;
    const f16* mem_v = memc + (long)(2 * L + 1) * 16384;
    const long ctxOff = (long)L * Bb * NCTXc * DIMd;   // element offset into context
    const f16* qnL = qn + (long)L * 2097152;

    // ctx slice -> f16; fused k|v projection: [4096x1024] @ [1024x2048]
    cvt_any<<<2048, 256, 0, stream>>>(d_in[1], cxf, 4194304, ctxOff, flag);
    gemm128<<<dim3(16, 32), 256, 0, stream>>>(cxf, wT + (long)(2 + 2 * L) * 1048576,
                                              tmpkv, 1024, 1024, 1024, 2048);
    kbuf_build<<<Bb * JP * Hh / 4, 256, 0, stream>>>(tmpkv, mem_k, kbuf);
    vt_build<<<Bb * Hh * (JP / 64), 256, 0, stream>>>(tmpkv + 1024, mem_v, vt);

    // scores: per (b,h): S[b][i][h][j] = qn_h[b,i] . kbuf_h[b,j], K=64
    gemm_bt<<<dim3(JP / 64, Nn / 64, Bb * Hh), 256, 0, stream>>>(qnL, kbuf, S, 64,
        1024, 1024, HJP,
        (long)Nn * 1024, (long)JP * 1024, (long)Nn * HJP,
        64, 64, JP, Hh);

    // fused talking-heads softmax via MFMA v6 (in-place), one block per (b,i) row
    softmax_mfma<<<Bb * Nn, 512, 0, stream>>>(S, thpre, thpost, hsp);

    // out_h = attn @ v : per (b,h): [1024 x 64], K = JP
    gemm_bt<<<dim3(1, Nn / 64, Bb * Hh), 256, 0, stream>>>(S, vt,
        av + (long)L * 1024, JP,
        HJP, JP, 2048,
        (long)Nn * HJP, (long)Hh * 64 * JP, (long)Nn * 2048,
        JP, (long)64 * JP, 64, Hh);
  }

  // final: out = [av1|av2] @ [wo1;wo2]  => [2048 x 1024], K=2048 (dtype-dispatched store)
  gemm128_dyn<<<dim3(8, 16), 256, 0, stream>>>(av, woT, d_out, 2048,
      2048, 2048, 1024, flag);
}

// Round 18
// 757.821 us; speedup vs baseline: 1.0500x; 1.0500x over previous
//
#include <hip/hip_runtime.h>
#include <hip/hip_bf16.h>

// Problem constants
#define Bb    2
#define Nn    1024
#define NCTXc 2048
#define DIMd  1024
#define Hh    16
#define DHd   64
#define NMEM  16
#define Jv    (NMEM + NCTXc)   // 2064 valid kv rows
#define JP    2112             // padded to multiple of 64
#define HJP   (Hh * JP)        // 33792: row stride of S ([b][i][h][j])
#define L2E   1.44269504088896f
#define LDH   1048             // staged half-row stride (1040 cols + 8 pad; 16B aligned, 2-way banks)

typedef _Float16 f16;
typedef _Float16 half8 __attribute__((ext_vector_type(8)));
typedef _Float16 half4 __attribute__((ext_vector_type(4)));
typedef float    f32x4 __attribute__((ext_vector_type(4)));

__device__ __forceinline__ float bf2f(unsigned short u){
  union { unsigned int i; float f; } v; v.i = ((unsigned)u) << 16; return v.f;
}
// sanitize: NaN -> 0, clamp to f16-safe range (identity on well-formed inputs)
__device__ __forceinline__ float fin(float v){
  v = (v == v) ? v : 0.f;
  return fminf(fmaxf(v, -65504.f), 65504.f);
}
// dtype-flag-dispatched input read. isf32: 1 = buffer holds float32, 0 = bf16.
__device__ __forceinline__ float ldin(const void* p, long i, int isf32){
  return isf32 ? ((const float*)p)[i] : bf2f(((const unsigned short*)p)[i]);
}
__device__ __forceinline__ half8 h8zero(){
  half8 v;
  #pragma unroll
  for (int j = 0; j < 8; j++) v[j] = (f16)0.f;
  return v;
}
// async global->LDS 16B copy (linear LDS dest = wave-uniform base + lane*16)
__device__ __forceinline__ void gload16(const f16* g, f16* l){
  __builtin_amdgcn_global_load_lds(
      (const __attribute__((address_space(1))) unsigned int*)g,
      (__attribute__((address_space(3))) unsigned int*)l, 16, 0, 0);
}

// ---------------- dtype probe ----------------
__global__ void detect_dtype(const void* __restrict__ p, int* __restrict__ flag, int n){
  const unsigned short* ub = (const unsigned short*)p;
  const float* fp = (const float*)p;
  int t = threadIdx.x;
  float bb = 0.f, bf = 0.f;
  for (int i = t; i < n; i += 64){
    float vb = bf2f(ub[i]);
    if (!(vb == vb) || fabsf(vb) > 1000.f) bb += 1.f;
    float vf = fp[i];
    if (!(vf == vf) || fabsf(vf) > 1000.f) bf += 1.f;
  }
  #pragma unroll
  for (int off = 32; off; off >>= 1){ bb += __shfl_xor(bb, off); bf += __shfl_xor(bf, off); }
  if (t == 0) *flag = (bf < bb) ? 1 : 0;
}

// ---------------- any-dtype -> f16 convert (sanitized), element offset in src dtype ----------------
__global__ __launch_bounds__(256) void cvt_any(const void* __restrict__ in, f16* __restrict__ out,
                                               long n, long off, const int* __restrict__ flag){
  int isf = *flag;
  long stride = (long)gridDim.x * 256;
  for (long i = (long)blockIdx.x * 256 + threadIdx.x; i < n; i += stride)
    out[i] = (f16)fin(ldin(in, off + i, isf));
}

// ---------------- merged small-input setup: blocks 0..15 -> memc, block 16 -> parc ----------------
// memc: 4 x 16384 f16 (mem_k1, mem_v1, mem_k2, mem_v2); parc: 1088 f32
// (th_pre1@0, th_post1@256, th_pre2@512, th_post2@768, sc1@1024, sc2@1040, hs1@1056, hs2@1072).
// Replaces 12 tiny launches with 1; value paths identical (fin + ldin).
__global__ __launch_bounds__(256) void setup_small(
    const void* mk1, const void* mv1, const void* mk2, const void* mv2,
    const void* thp1, const void* tho1, const void* thp2, const void* tho2,
    const void* sc1, const void* sc2, const void* hs1, const void* hs2,
    f16* __restrict__ memc, float* __restrict__ parc, const int* __restrict__ flag)
{
  int isf = *flag;
  int b = blockIdx.x, t = threadIdx.x;
  if (b < 16){
    const void* src = (b < 8) ? ((b < 4) ? mk1 : mv1) : ((b < 12) ? mk2 : mv2);
    int base = (b & 3) * 4096;
    long gbase = (long)(b >> 2) * 16384;
    for (int i = t; i < 4096; i += 256)
      memc[gbase + base + i] = (f16)fin(ldin(src, base + i, isf));
  } else {
    for (int i = t; i < 1088; i += 256){
      const void* src; int local;
      if      (i < 256)  { src = thp1; local = i; }
      else if (i < 512)  { src = tho1; local = i - 256; }
      else if (i < 768)  { src = thp2; local = i - 512; }
      else if (i < 1024) { src = tho2; local = i - 768; }
      else if (i < 1040) { src = sc1;  local = i - 1024; }
      else if (i < 1056) { src = sc2;  local = i - 1040; }
      else if (i < 1072) { src = hs1;  local = i - 1056; }
      else               { src = hs2;  local = i - 1072; }
      parc[i] = fin(ldin(src, local, isf));
    }
  }
}

// ---------------- merged transpose of all 8 weight matrices (all 1024x1024 inputs) ----------------
// z = 0..5: wq1,wk1,wv1,wq2,wk2,wv2 -> wT slots {0,2,3,1,4,5} (ldo 1024);
// z = 6..7: wo1,wo2 -> woT + z*1024 (ldo 2048). out[c][r] = in[r][c]; replaces 8 launches with 1.
__global__ __launch_bounds__(256) void transpose8(
    const void* w0, const void* w1, const void* w2, const void* w3,
    const void* w4, const void* w5, const void* o0, const void* o1,
    f16* __restrict__ wT, f16* __restrict__ woT, const int* __restrict__ flag)
{
  __shared__ f16 tile[32][33];
  int isf = *flag;
  int z = blockIdx.z;
  const void* in; f16* out; long ldo;
  switch (z){
    case 0:  in = w0; out = wT + 0l * 1048576; ldo = 1024; break;
    case 1:  in = w1; out = wT + 2l * 1048576; ldo = 1024; break;
    case 2:  in = w2; out = wT + 3l * 1048576; ldo = 1024; break;
    case 3:  in = w3; out = wT + 1l * 1048576; ldo = 1024; break;
    case 4:  in = w4; out = wT + 4l * 1048576; ldo = 1024; break;
    case 5:  in = w5; out = wT + 5l * 1048576; ldo = 1024; break;
    case 6:  in = o0; out = woT;               ldo = 2048; break;
    default: in = o1; out = woT + 1024;        ldo = 2048; break;
  }
  int r0 = blockIdx.y * 32, c0 = blockIdx.x * 32;
  int tr = threadIdx.x >> 5, tc = threadIdx.x & 31;
  #pragma unroll
  for (int k = 0; k < 4; k++){
    int r = tr + k * 8;
    tile[r][tc] = (f16)fin(ldin(in, (long)(r0 + r) * 1024 + c0 + tc, isf));
  }
  __syncthreads();
  #pragma unroll
  for (int k = 0; k < 4; k++){
    int r = tr + k * 8;
    out[(long)(c0 + r) * ldo + r0 + tc] = tile[tc][r];
  }
}

// ---------------- 128x128-tile GEMM (f16 in/out): C[m][n] = sum_k A[m][k]*Bt[n][k] ----------------
// m97-style: BK=32, global_load_lds width 16 into LINEAR [128][32] LDS, 4 waves of 4x4
// 16x16x32 fragments, 2-barrier K-loop. M,N multiples of 128; K multiple of 32.
__global__ __launch_bounds__(256) void gemm128(
    const f16* __restrict__ A, const f16* __restrict__ Bt, f16* __restrict__ C,
    int K, long lda, long ldb, long ldc)
{
  __shared__ __align__(16) f16 As[128 * 32];
  __shared__ __align__(16) f16 Bs[128 * 32];
  long m0 = (long)blockIdx.y * 128, n0 = (long)blockIdx.x * 128;
  int t = threadIdx.x;
  int wave = t >> 6, lane = t & 63;
  int wm = (wave >> 1) * 64, wn = (wave & 1) * 64;
  int fr = lane & 15, fq = lane >> 4;
  int sr = t >> 2, scc = (t & 3) * 8;   // staging: 4 thr/row x 8 f16, 64 rows/issue

  f32x4 acc[4][4];
  #pragma unroll
  for (int a = 0; a < 4; a++)
    #pragma unroll
    for (int b = 0; b < 4; b++) acc[a][b] = (f32x4){0.f, 0.f, 0.f, 0.f};

  const f16* Ap  = A  + (m0 + sr) * lda + scc;
  const f16* Ap2 = Ap + 64 * lda;
  const f16* Bp  = Bt + (n0 + sr) * ldb + scc;
  const f16* Bp2 = Bp + 64 * ldb;
  f16* Ad  = As + t * 8;        // byte t*16: linear dest (row-major [64][32])
  f16* Ad2 = As + 2048 + t * 8;
  f16* Bd  = Bs + t * 8;
  f16* Bd2 = Bs + 2048 + t * 8;

  for (int k0 = 0; k0 < K; k0 += 32){
    __syncthreads();              // prev tile fully consumed before overwrite
    gload16(Ap  + k0, Ad);
    gload16(Ap2 + k0, Ad2);
    gload16(Bp  + k0, Bd);
    gload16(Bp2 + k0, Bd2);
    __syncthreads();              // drains vmcnt(0): loads landed
    half8 bfr[4];
    #pragma unroll
    for (int tj = 0; tj < 4; tj++)
      bfr[tj] = *(const half8*)&Bs[(wn + 16 * tj + fr) * 32 + fq * 8];
    #pragma unroll
    for (int ti = 0; ti < 4; ti++){
      half8 af = *(const half8*)&As[(wm + 16 * ti + fr) * 32 + fq * 8];
      #pragma unroll
      for (int tj = 0; tj < 4; tj++)
        acc[ti][tj] = __builtin_amdgcn_mfma_f32_16x16x32_f16(af, bfr[tj], acc[ti][tj], 0, 0, 0);
    }
  }
  #pragma unroll
  for (int ti = 0; ti < 4; ti++)
    #pragma unroll
    for (int tj = 0; tj < 4; tj++)
      #pragma unroll
      for (int r = 0; r < 4; r++){
        long row = m0 + wm + 16 * ti + fq * 4 + r;
        long col = n0 + wn + 16 * tj + fr;
        C[row * ldc + col] = (f16)acc[ti][tj][r];
      }
}

// ---------------- same, dtype-dispatched output store (final GEMM) ----------------
__global__ __launch_bounds__(256) void gemm128_dyn(
    const f16* __restrict__ A, const f16* __restrict__ Bt, void* __restrict__ C,
    int K, long lda, long ldb, long ldc, const int* __restrict__ flag)
{
  int isf = *flag;
  __shared__ __align__(16) f16 As[128 * 32];
  __shared__ __align__(16) f16 Bs[128 * 32];
  long m0 = (long)blockIdx.y * 128, n0 = (long)blockIdx.x * 128;
  int t = threadIdx.x;
  int wave = t >> 6, lane = t & 63;
  int wm = (wave >> 1) * 64, wn = (wave & 1) * 64;
  int fr = lane & 15, fq = lane >> 4;
  int sr = t >> 2, scc = (t & 3) * 8;

  f32x4 acc[4][4];
  #pragma unroll
  for (int a = 0; a < 4; a++)
    #pragma unroll
    for (int b = 0; b < 4; b++) acc[a][b] = (f32x4){0.f, 0.f, 0.f, 0.f};

  const f16* Ap  = A  + (m0 + sr) * lda + scc;
  const f16* Ap2 = Ap + 64 * lda;
  const f16* Bp  = Bt + (n0 + sr) * ldb + scc;
  const f16* Bp2 = Bp + 64 * ldb;
  f16* Ad  = As + t * 8;
  f16* Ad2 = As + 2048 + t * 8;
  f16* Bd  = Bs + t * 8;
  f16* Bd2 = Bs + 2048 + t * 8;

  for (int k0 = 0; k0 < K; k0 += 32){
    __syncthreads();
    gload16(Ap  + k0, Ad);
    gload16(Ap2 + k0, Ad2);
    gload16(Bp  + k0, Bd);
    gload16(Bp2 + k0, Bd2);
    __syncthreads();
    half8 bfr[4];
    #pragma unroll
    for (int tj = 0; tj < 4; tj++)
      bfr[tj] = *(const half8*)&Bs[(wn + 16 * tj + fr) * 32 + fq * 8];
    #pragma unroll
    for (int ti = 0; ti < 4; ti++){
      half8 af = *(const half8*)&As[(wm + 16 * ti + fr) * 32 + fq * 8];
      #pragma unroll
      for (int tj = 0; tj < 4; tj++)
        acc[ti][tj] = __builtin_amdgcn_mfma_f32_16x16x32_f16(af, bfr[tj], acc[ti][tj], 0, 0, 0);
    }
  }
  #pragma unroll
  for (int ti = 0; ti < 4; ti++)
    #pragma unroll
    for (int tj = 0; tj < 4; tj++)
      #pragma unroll
      for (int r = 0; r < 4; r++){
        long row = m0 + wm + 16 * ti + fq * 4 + r;
        long col = n0 + wn + 16 * tj + fr;
        float v = acc[ti][tj][r];
        if (isf) ((float*)C)[row * ldc + col] = v;
        else     ((__hip_bfloat16*)C)[row * ldc + col] = __float2bfloat16(v);
      }
}

// ---------------- generic batched GEMM: C[m][n] = sum_k A[m][k]*Bt[n][k], z=(zb,zh) ----------------
// gload16 (async DMA) staging into LINEAR [64][32] LDS; C-tile staged through LDS -> half8
// coalesced stores. Arithmetic order identical to previous versions.
__global__ __launch_bounds__(256) void gemm_bt(
    const f16* __restrict__ A, const f16* __restrict__ Bt, f16* __restrict__ C,
    int K, long lda, long ldb, long ldc,
    long sAb, long sBb, long sCb, long sAh, long sBh, long sCh, int nh)
{
  int z = blockIdx.z;
  int zb = z / nh, zh = z - zb * nh;
  A  += (long)zb * sAb + (long)zh * sAh;
  Bt += (long)zb * sBb + (long)zh * sBh;
  C  += (long)zb * sCb + (long)zh * sCh;
  long m0 = (long)blockIdx.y * 64, n0 = (long)blockIdx.x * 64;

  __shared__ __align__(16) f16 As[64 * 32];
  __shared__ __align__(16) f16 Bs[64 * 32];
  __shared__ __align__(16) f16 Cs[64 * 64];
  int t = threadIdx.x;
  int wave = t >> 6, lane = t & 63;
  int wm = (wave >> 1) * 32, wn = (wave & 1) * 32;
  int fr = lane & 15, fq = lane >> 4;
  int sr = t >> 2, scc = (t & 3) * 8;

  f32x4 acc[2][2];
  #pragma unroll
  for (int a = 0; a < 2; a++)
    #pragma unroll
    for (int b = 0; b < 2; b++) acc[a][b] = (f32x4){0.f, 0.f, 0.f, 0.f};

  const f16* Ap = A  + (m0 + sr) * lda + scc;
  const f16* Bp = Bt + (n0 + sr) * ldb + scc;
  f16* Ad = As + t * 8;          // byte t*16: linear dest (row-major [64][32])
  f16* Bd = Bs + t * 8;

  for (int k0 = 0; k0 < K; k0 += 32){
    __syncthreads();             // prev tile fully consumed before overwrite
    gload16(Ap + k0, Ad);
    gload16(Bp + k0, Bd);
    __syncthreads();             // drains vmcnt(0): loads landed
    #pragma unroll
    for (int ti = 0; ti < 2; ti++){
      half8 af = *(const half8*)&As[(wm + 16 * ti + fr) * 32 + fq * 8];
      #pragma unroll
      for (int tj = 0; tj < 2; tj++){
        half8 bf = *(const half8*)&Bs[(wn + 16 * tj + fr) * 32 + fq * 8];
        acc[ti][tj] = __builtin_amdgcn_mfma_f32_16x16x32_f16(af, bf, acc[ti][tj], 0, 0, 0);
      }
    }
  }
  // stage C tile in LDS (value-identical), then coalesced half8 stores
  __syncthreads();
  #pragma unroll
  for (int ti = 0; ti < 2; ti++)
    #pragma unroll
    for (int tj = 0; tj < 2; tj++)
      #pragma unroll
      for (int r = 0; r < 4; r++)
        Cs[(wm + 16 * ti + fq * 4 + r) * 64 + wn + 16 * tj + fr] = (f16)acc[ti][tj][r];
  __syncthreads();
  #pragma unroll
  for (int it = 0; it < 2; it++){
    int idx = t + it * 256;          // 0..511: row = idx>>3, col8 = (idx&7)*8
    int row = idx >> 3, c8 = (idx & 7) * 8;
    *(half8*)(C + (m0 + row) * ldc + n0 + c8) = *(const half8*)&Cs[row * 64 + c8];
  }
}

// ---------------- q: l2norm per head + fold per-head scale (qp row stride 2048) ----------------
__global__ __launch_bounds__(256) void qn_build(const f16* __restrict__ qp, f16* __restrict__ qn,
                                                const float* __restrict__ scale_p){
  int row = blockIdx.x;                 // 0..B*N-1
  int wave = threadIdx.x >> 6, lane = threadIdx.x & 63;
  #pragma unroll
  for (int hh = 0; hh < 4; hh++){
    int h = wave * 4 + hh;
    float v = (float)qp[(long)row * 2048 + h * 64 + lane];
    float ss = v * v;
    #pragma unroll
    for (int off = 32; off; off >>= 1) ss += __shfl_xor(ss, off);
    float sc = 1.0f / fmaxf(__expf(scale_p[h]), 0.01f);
    float o = v / fmaxf(sqrtf(ss), 1e-12f) * sc;
    qn[(long)row * 1024 + h * 64 + lane] = (f16)o;
  }
}

// ---------------- k buffer: mem_k prepended, l2norm, zero pad (kp row stride 2048) ----------------
__global__ __launch_bounds__(256) void kbuf_build(const f16* __restrict__ kp,
                                                  const f16* __restrict__ mem_k,
                                                  f16* __restrict__ kbuf){
  int id = blockIdx.x * 4 + (threadIdx.x >> 6);  // (b*JP + j)*16 + h
  int lane = threadIdx.x & 63;
  int h = id & 15; int bj = id >> 4; int j = bj % JP; int b = bj / JP;
  float v;
  if (j < NMEM)              v = (float)mem_k[(h * NMEM + j) * 64 + lane];
  else if (j < NMEM + NCTXc) v = (float)kp[((long)b * NCTXc + (j - NMEM)) * 2048 + h * 64 + lane];
  else                       v = 0.f;
  float ss = v * v;
  #pragma unroll
  for (int off = 32; off; off >>= 1) ss += __shfl_xor(ss, off);
  float o = v / fmaxf(sqrtf(ss), 1e-12f);
  kbuf[((long)b * JP + j) * 1024 + h * 64 + lane] = (f16)o;
}

// ---------------- v buffer, transposed per head: vt[(b,h)][d][j] (vp row stride 2048) ----------------
__global__ __launch_bounds__(256) void vt_build(const f16* __restrict__ vp,
                                                const f16* __restrict__ mem_v,
                                                f16* __restrict__ vt){
  __shared__ f16 tile[64][72];
  int id = blockIdx.x;
  int jt = id % (JP / 64); int h = (id / (JP / 64)) & 15; int b = id / (16 * (JP / 64));
  int j0 = jt * 64;
  int t = threadIdx.x;
  #pragma unroll
  for (int rep = 0; rep < 2; rep++){
    int idx = t + rep * 256;
    int jj = idx >> 3, c8 = (idx & 7) * 8;
    int j = j0 + jj;
    half8 v;
    if (j < NMEM){
      v = *(const half8*)(mem_v + (h * NMEM + j) * 64 + c8);
    } else if (j < NMEM + NCTXc){
      v = *(const half8*)(vp + ((long)b * NCTXc + (j - NMEM)) * 2048 + h * 64 + c8);
    } else {
      v = h8zero();
    }
    *(half8*)&tile[jj][c8] = v;
  }
  __syncthreads();
  #pragma unroll
  for (int rep = 0; rep < 2; rep++){
    int idx = t + rep * 256;
    int d = idx >> 3, j8 = (idx & 7) * 8;
    half8 o;
    #pragma unroll
    for (int k = 0; k < 8; k++) o[k] = tile[j8 + k][d];
    *(half8*)(vt + (((long)(b * 16 + h) * 64 + d) * JP) + j0 + j8) = o;
  }
}

// ---------------- fused talking-heads softmax via MFMA, v5 (best measured) ----------------
// v2 structure with T14-style issue-early staging: TWO LDS tiles (67 KB), both halves
// staged back-to-back at kernel entry under ONE barrier, then both premix/stats phases
// run uninterrupted. Sweep 2 is the register-only path with scalar stores.
__global__ __launch_bounds__(512) void softmax_mfma(
    f16* __restrict__ S,
    const float* __restrict__ th_pre,
    const float* __restrict__ th_post,
    const float* __restrict__ hs)
{
  __shared__ __align__(16) f16 tile0[16 * LDH];  // 33536 B (cols 0..1039)
  __shared__ __align__(16) f16 tile1[16 * LDH];  // 33536 B (cols 1040..2063)
  __shared__ float msh[8][16], lsh[8][16];
  __shared__ float Mf[16], Li[16];

  int t = threadIdx.x, wave = t >> 6, lane = t & 63;
  int r16 = lane & 15;                    // fragment row/col index
  int hb4 = (lane >> 4) * 4;              // k-group base (4 heads per lane group)
  int sr  = t >> 5, sc = t & 31;          // staging: row 0..15, col-thread 0..31
  f16* Srow = S + (long)blockIdx.x * HJP;

  // pre-mix A fragment: A[g = r16][h = hb4+j] = th_pre[g][h], hi/lo f16 split
  half4 ahi, alo;
  #pragma unroll
  for (int j = 0; j < 4; j++){
    float a = th_pre[r16 * 16 + hb4 + j];
    ahi[j] = (f16)a; alo[j] = (f16)(a - (float)ahi[j]);
  }

  float m[4], l[4];
  #pragma unroll
  for (int r = 0; r < 4; r++){ m[r] = -1e30f; l[r] = 0.f; }

  half4 msave[17];
  const f32x4 z4 = (f32x4){0.f, 0.f, 0.f, 0.f};

  // ---- stage BOTH halves up front (loads overlap; one barrier) ----
  #pragma unroll
  for (int it = 0; it < 5; it++){
    int c8 = sc + it * 32;
    if (c8 < 130)
      *(half8*)&tile0[sr * LDH + c8 * 8] = *(const half8*)(Srow + (long)sr * JP + c8 * 8);
  }
  #pragma unroll
  for (int it = 0; it < 4; it++){
    int c8 = sc + it * 32;
    *(half8*)&tile1[sr * LDH + c8 * 8] = *(const half8*)(Srow + (long)sr * JP + 1040 + c8 * 8);
  }
  __syncthreads();

  // ---- sweep 1: premix + stats, both halves back-to-back ----
  #pragma unroll
  for (int cc = 0; cc < 9; cc++){
    int c = wave + cc * 8;
    if (c < 65){
      int lc = c * 16 + r16;
      half4 b;
      #pragma unroll
      for (int j = 0; j < 4; j++) b[j] = tile0[(hb4 + j) * LDH + lc];
      f32x4 acc = __builtin_amdgcn_mfma_f32_16x16x16f16(alo, b, z4, 0, 0, 0);
      acc = __builtin_amdgcn_mfma_f32_16x16x16f16(ahi, b, acc, 0, 0, 0);
      half4 hh;
      #pragma unroll
      for (int r = 0; r < 4; r++){
        float u = fminf(fmaxf(acc[r], -60.f), 78.f);
        m[r] = fmaxf(m[r], u);
        l[r] += exp2f(u * L2E);
        hh[r] = (f16)u;
      }
      msave[cc] = hh;
    }
  }
  #pragma unroll
  for (int cc = 0; cc < 8; cc++){
    int c = 65 + wave + cc * 8;
    int lc = c * 16 - 1040 + r16;
    half4 b;
    #pragma unroll
    for (int j = 0; j < 4; j++) b[j] = tile1[(hb4 + j) * LDH + lc];
    f32x4 acc = __builtin_amdgcn_mfma_f32_16x16x16f16(alo, b, z4, 0, 0, 0);
    acc = __builtin_amdgcn_mfma_f32_16x16x16f16(ahi, b, acc, 0, 0, 0);
    half4 hh;
    #pragma unroll
    for (int r = 0; r < 4; r++){
      float u = fminf(fmaxf(acc[r], -60.f), 78.f);
      m[r] = fmaxf(m[r], u);
      l[r] += exp2f(u * L2E);
      hh[r] = (f16)u;
    }
    msave[9 + cc] = hh;
  }

  // ---- reduce (m,l): plain fmax/add butterfly within 16-lane groups, then waves ----
  #pragma unroll
  for (int off = 1; off < 16; off <<= 1){
    #pragma unroll
    for (int r = 0; r < 4; r++){
      m[r] = fmaxf(m[r], __shfl_xor(m[r], off));
      l[r] += __shfl_xor(l[r], off);
    }
  }
  if (r16 == 0){
    #pragma unroll
    for (int r = 0; r < 4; r++){ msh[wave][hb4 + r] = m[r]; lsh[wave][hb4 + r] = l[r]; }
  }
  __syncthreads();
  if (t < 16){
    float mf_ = msh[0][t], lf = lsh[0][t];
    #pragma unroll
    for (int w = 1; w < 8; w++){ mf_ = fmaxf(mf_, msh[w][t]); lf += lsh[w][t]; }
    Mf[t] = mf_;
    Li[t] = fin(exp2f(mf_ * L2E) / lf);
  }
  __syncthreads();

  // post-mix A fragment: C[p = r16][g = hb4+j] = th_post[p][g]*hs[p]*2^(M_g*L2E)/l_g
  half4 chi, clo;
  float hsv = hs[r16];
  #pragma unroll
  for (int j = 0; j < 4; j++){
    float cc2 = th_post[r16 * 16 + hb4 + j] * hsv * Li[hb4 + j];
    chi[j] = (f16)cc2; clo[j] = (f16)(cc2 - (float)chi[j]);
  }
  float mf[4];
  #pragma unroll
  for (int r = 0; r < 4; r++) mf[r] = Mf[hb4 + r];

  // ---- sweep 2: register-only exp + post-mix + store ----
  #pragma unroll
  for (int cc = 0; cc < 9; cc++){
    int c = wave + cc * 8;
    if (c < 65){
      half4 h4 = msave[cc];
      half4 ehi, elo;
      #pragma unroll
      for (int r = 0; r < 4; r++){
        float e = exp2f(((float)h4[r] - mf[r]) * L2E);
        ehi[r] = (f16)e; elo[r] = (f16)(e - (float)ehi[r]);
      }
      f32x4 o = __builtin_amdgcn_mfma_f32_16x16x16f16(chi, ehi, z4, 0, 0, 0);
      o = __builtin_amdgcn_mfma_f32_16x16x16f16(clo, ehi, o, 0, 0, 0);
      o = __builtin_amdgcn_mfma_f32_16x16x16f16(chi, elo, o, 0, 0, 0);
      int col = c * 16 + r16;
      #pragma unroll
      for (int r = 0; r < 4; r++) Srow[(hb4 + r) * JP + col] = (f16)o[r];
    }
  }
  #pragma unroll
  for (int cc = 0; cc < 8; cc++){
    int c = 65 + wave + cc * 8;
    half4 h4 = msave[9 + cc];
    half4 ehi, elo;
    #pragma unroll
    for (int r = 0; r < 4; r++){
      float e = exp2f(((float)h4[r] - mf[r]) * L2E);
      ehi[r] = (f16)e; elo[r] = (f16)(e - (float)ehi[r]);
    }
    f32x4 o = __builtin_amdgcn_mfma_f32_16x16x16f16(chi, ehi, z4, 0, 0, 0);
    o = __builtin_amdgcn_mfma_f32_16x16x16f16(clo, ehi, o, 0, 0, 0);
    o = __builtin_amdgcn_mfma_f32_16x16x16f16(chi, elo, o, 0, 0, 0);
    int col = c * 16 + r16;
    #pragma unroll
    for (int r = 0; r < 4; r++) Srow[(hb4 + r) * JP + col] = (f16)o[r];
  }
}

// ---------------- launch ----------------
extern "C" void kernel_launch(void* const* d_in, const int* in_sizes, int n_in,
                              void* d_out, int out_size, void* d_ws, size_t ws_size,
                              hipStream_t stream)
{
  (void)in_sizes; (void)n_in; (void)out_size; (void)ws_size;
  int* flag = (int*)d_ws;
  f16* ws   = (f16*)d_ws + 8;        // keep 16B alignment
  f16* wT   = ws;                    //  6,291,456: slots [wq1T][wq2T][wk1T][wv1T][wk2T][wv2T]
  f16* woT  = wT   + 6291456;        //  2,097,152 ([1024 x 2048])
  f16* qn   = woT  + 2097152;        //  4,194,304 (qn layer0, qn layer1)
  f16* kbuf = qn   + 4194304;        //  4,325,376
  f16* vt   = kbuf + 4325376;        //  4,325,376
  f16* av   = vt   + 4325376;        //  4,194,304 ([B*N x 2048])
  f16* memc = av   + 4194304;        //  65,536 (mem_k1,mem_v1,mem_k2,mem_v2)
  float* parc = (float*)(memc + 65536); // 1088 f32 (th_pre1,th_post1,th_pre2,th_post2,sc1,sc2,hs1,hs2)
  f16* S    = (f16*)(parc + 1088);   //  69,206,016 ([b][i][16][JP])
  // scratch aliased inside S (all dead before the score GEMM writes S):
  f16* tmpkv = S;                    //  8,388,608 ([4096 x 2048]: k cols 0..1023, v cols 1024..2047)
  f16* tmpq  = S + 8388608;          //  4,194,304 ([2048 x 2048]: q1 cols 0..1023, q2 cols 1024..2047)
  f16* xf    = S + 12582912;         //  2,097,152 (x as f16)
  f16* cxf   = S + 14680064;         //  4,194,304 (ctx layer slice as f16)

  // dtype probe on x
  detect_dtype<<<1, 64, 0, stream>>>(d_in[0], flag, 4096);

  // merged setup: mem tensors -> f16, small params -> f32 pack (was 12 launches)
  setup_small<<<17, 256, 0, stream>>>(
      d_in[14], d_in[15], d_in[16], d_in[17],
      d_in[8], d_in[9], d_in[10], d_in[11],
      d_in[12], d_in[13], d_in[18], d_in[19],
      memc, parc, flag);

  // merged transpose of all 8 weight matrices (was 8 launches)
  transpose8<<<dim3(32, 32, 8), 256, 0, stream>>>(
      d_in[2], d_in[3], d_in[4], d_in[5], d_in[6], d_in[7],
      d_in[20], d_in[21], wT, woT, flag);

  // x -> f16 once; q projection for BOTH layers: [2048x1024] @ [1024x2048]
  cvt_any<<<1024, 256, 0, stream>>>(d_in[0], xf, 2097152, 0, flag);
  gemm128<<<dim3(16, 16), 256, 0, stream>>>(xf, wT, tmpq, 1024, 1024, 1024, 2048);
  for (int L = 0; L < 2; L++)
    qn_build<<<Bb * Nn, 256, 0, stream>>>(tmpq + (long)L * 1024, qn + (long)L * 2097152,
                                          parc + 1024 + (long)L * 16);

  for (int L = 0; L < 2; L++){
    const float* thpre  = parc + (long)L * 512;
    const float* thpost = parc + (long)L * 512 + 256;
    const float* hsp    = parc + 1056 + (long)L * 16;
    const f16* mem_k = memc + (long)(2 * L) * 16384;
    const f16* mem_v = memc + (long)(2 * L + 1) * 16384;
    const long ctxOff = (long)L * Bb * NCTXc * DIMd;   // element offset into context
    const f16* qnL = qn + (long)L * 2097152;

    // ctx slice -> f16; fused k|v projection: [4096x1024] @ [1024x2048]
    cvt_any<<<2048, 256, 0, stream>>>(d_in[1], cxf, 4194304, ctxOff, flag);
    gemm128<<<dim3(16, 32), 256, 0, stream>>>(cxf, wT + (long)(2 + 2 * L) * 1048576,
                                              tmpkv, 1024, 1024, 1024, 2048);
    kbuf_build<<<Bb * JP * Hh / 4, 256, 0, stream>>>(tmpkv, mem_k, kbuf);
    vt_build<<<Bb * Hh * (JP / 64), 256, 0, stream>>>(tmpkv + 1024, mem_v, vt);

    // scores: per (b,h): S[b][i][h][j] = qn_h[b,i] . kbuf_h[b,j], K=64
    gemm_bt<<<dim3(JP / 64, Nn / 64, Bb * Hh), 256, 0, stream>>>(qnL, kbuf, S, 64,
        1024, 1024, HJP,
        (long)Nn * 1024, (long)JP * 1024, (long)Nn * HJP,
        64, 64, JP, Hh);

    // fused talking-heads softmax via MFMA v5 (in-place), one block per (b,i) row
    softmax_mfma<<<Bb * Nn, 512, 0, stream>>>(S, thpre, thpost, hsp);

    // out_h = attn @ v : per (b,h): [1024 x 64], K = JP
    gemm_bt<<<dim3(1, Nn / 64, Bb * Hh), 256, 0, stream>>>(S, vt,
        av + (long)L * 1024, JP,
        HJP, JP, 2048,
        (long)Nn * HJP, (long)Hh * 64 * JP, (long)Nn * 2048,
        JP, (long)64 * JP, 64, Hh);
  }

  // final: out = [av1|av2] @ [wo1;wo2]  => [2048 x 1024], K=2048 (dtype-dispatched store)
  gemm128_dyn<<<dim3(8, 16), 256, 0, stream>>>(av, woT, d_out, 2048,
      2048, 2048, 1024, flag);
}